// Round 3
// baseline (180.859 us; speedup 1.0000x reference)
//
#include <hip/hip_runtime.h>

// CGM: channel-group max filter.
// x: [B=32, C=256, W=56, H=56] fp32, groups of g=4 along C.
// out[b,c,w,h] = x if (x == max over its group) && (x > 0), clamped to max_clamp; else 0.
//
// Memory-bound streaming: 102.8 MB in + 102.8 MB out, zero reuse -> nt loads/stores.
// Each thread handles 8 consecutive spatial positions (2x float4) across all 4
// channels of one group: 8 nt float4 loads + 8 nt float4 stores (128 B/thread each way).

#define SPATIAL 3136      // 56*56
#define SPATIAL8 392      // SPATIAL/8
#define GROUPS_TOTAL (32 * 64)  // B * (C/group_size)

typedef float v4f __attribute__((ext_vector_type(4)));

__device__ __forceinline__ v4f vmax4(v4f a, v4f b) {
    v4f r;
    r.x = fmaxf(a.x, b.x); r.y = fmaxf(a.y, b.y);
    r.z = fmaxf(a.z, b.z); r.w = fmaxf(a.w, b.w);
    return r;
}

__global__ __launch_bounds__(256) void CGM_16707422781821_kernel(
    const float* __restrict__ x,
    float* __restrict__ out,
    const float* __restrict__ max_clamp_p) {
    const int t = blockIdx.x * blockDim.x + threadIdx.x;
    // t in [0, GROUPS_TOTAL * SPATIAL8); exact grid, no bounds check.
    const int plane = t / SPATIAL8;   // which (b, group)
    const int pos8  = t - plane * SPATIAL8;

    const float clampv = *max_clamp_p;

    // base element offset of channel 0 of this group at this spatial chunk
    const long base = (long)plane * (4L * SPATIAL) + (long)pos8 * 8;

    // two float4 halves (a = +0, b = +4) for each of the 4 channels
    v4f v0a = __builtin_nontemporal_load((const v4f*)(x + base));
    v4f v0b = __builtin_nontemporal_load((const v4f*)(x + base + 4));
    v4f v1a = __builtin_nontemporal_load((const v4f*)(x + base + SPATIAL));
    v4f v1b = __builtin_nontemporal_load((const v4f*)(x + base + SPATIAL + 4));
    v4f v2a = __builtin_nontemporal_load((const v4f*)(x + base + 2 * SPATIAL));
    v4f v2b = __builtin_nontemporal_load((const v4f*)(x + base + 2 * SPATIAL + 4));
    v4f v3a = __builtin_nontemporal_load((const v4f*)(x + base + 3 * SPATIAL));
    v4f v3b = __builtin_nontemporal_load((const v4f*)(x + base + 3 * SPATIAL + 4));

    // elementwise group max across the 4 channels
    v4f ma = vmax4(vmax4(v0a, v1a), vmax4(v2a, v3a));
    v4f mb = vmax4(vmax4(v0b, v1b), vmax4(v2b, v3b));

#define FILT(v, mm) (((v) == (mm) && (v) > 0.0f) ? fminf((v), clampv) : 0.0f)
#define FILT4(o, v, mm) \
    o.x = FILT(v.x, mm.x); o.y = FILT(v.y, mm.y); \
    o.z = FILT(v.z, mm.z); o.w = FILT(v.w, mm.w);

    v4f o0a, o0b, o1a, o1b, o2a, o2b, o3a, o3b;
    FILT4(o0a, v0a, ma); FILT4(o0b, v0b, mb);
    FILT4(o1a, v1a, ma); FILT4(o1b, v1b, mb);
    FILT4(o2a, v2a, ma); FILT4(o2b, v2b, mb);
    FILT4(o3a, v3a, ma); FILT4(o3b, v3b, mb);
#undef FILT4
#undef FILT

    __builtin_nontemporal_store(o0a, (v4f*)(out + base));
    __builtin_nontemporal_store(o0b, (v4f*)(out + base + 4));
    __builtin_nontemporal_store(o1a, (v4f*)(out + base + SPATIAL));
    __builtin_nontemporal_store(o1b, (v4f*)(out + base + SPATIAL + 4));
    __builtin_nontemporal_store(o2a, (v4f*)(out + base + 2 * SPATIAL));
    __builtin_nontemporal_store(o2b, (v4f*)(out + base + 2 * SPATIAL + 4));
    __builtin_nontemporal_store(o3a, (v4f*)(out + base + 3 * SPATIAL));
    __builtin_nontemporal_store(o3b, (v4f*)(out + base + 3 * SPATIAL + 4));
}

extern "C" void kernel_launch(void* const* d_in, const int* in_sizes, int n_in,
                              void* d_out, int out_size, void* d_ws, size_t ws_size,
                              hipStream_t stream) {
    const float* x = (const float*)d_in[0];
    // d_in[1] = group_size (int, ==4, structural — hardcoded)
    const float* max_clamp_p = (const float*)d_in[2];
    float* out = (float*)d_out;

    const int total_threads = GROUPS_TOTAL * SPATIAL8;  // 802,816
    const int block = 256;
    const int grid = total_threads / block;             // 3136, exact
    CGM_16707422781821_kernel<<<grid, block, 0, stream>>>(x, out, max_clamp_p);
}

// Round 4
// 172.891 us; speedup vs baseline: 1.0461x; 1.0461x over previous
//
#include <hip/hip_runtime.h>

// CGM: channel-group max filter.
// x: [B=32, C=256, W=56, H=56] fp32, groups of g=4 along C.
// out[b,c,w,h] = x if (x == max over its group) && (x > 0), clamped to max_clamp; else 0.
//
// Memory-bound streaming: 102.8 MB in + 102.8 MB out, zero reuse -> nt loads/stores.
// Each thread handles 4 consecutive spatial positions (float4) across all 4
// channels of one group. Lane i at base + i*4 floats => each wave vmem
// instruction is one contiguous 1 KiB segment (perfect coalescing).
// NOTE: 8-floats/thread variant regressed (180.9 vs 173.5 us): 32 B lane
// stride made every load span 2x the cache lines. Keep 4/thread.

#define SPATIAL 3136      // 56*56
#define SPATIAL4 784      // SPATIAL/4
#define GROUPS_TOTAL (32 * 64)  // B * (C/group_size)

typedef float v4f __attribute__((ext_vector_type(4)));

__global__ __launch_bounds__(256) void CGM_16707422781821_kernel(
    const float* __restrict__ x,
    float* __restrict__ out,
    const float* __restrict__ max_clamp_p) {
    const int t = blockIdx.x * blockDim.x + threadIdx.x;
    // t in [0, GROUPS_TOTAL * SPATIAL4); exact grid, no bounds check.
    const int plane = t / SPATIAL4;   // which (b, group)
    const int pos4  = t - plane * SPATIAL4;

    const float clampv = *max_clamp_p;

    // base element offset of channel 0 of this group at this spatial chunk
    const long base = (long)plane * (4L * SPATIAL) + (long)pos4 * 4;

    const v4f v0 = __builtin_nontemporal_load((const v4f*)(x + base));
    const v4f v1 = __builtin_nontemporal_load((const v4f*)(x + base + SPATIAL));
    const v4f v2 = __builtin_nontemporal_load((const v4f*)(x + base + 2 * SPATIAL));
    const v4f v3 = __builtin_nontemporal_load((const v4f*)(x + base + 3 * SPATIAL));

    // elementwise group max across the 4 channels
    v4f m;
    m.x = fmaxf(fmaxf(v0.x, v1.x), fmaxf(v2.x, v3.x));
    m.y = fmaxf(fmaxf(v0.y, v1.y), fmaxf(v2.y, v3.y));
    m.z = fmaxf(fmaxf(v0.z, v1.z), fmaxf(v2.z, v3.z));
    m.w = fmaxf(fmaxf(v0.w, v1.w), fmaxf(v2.w, v3.w));

#define FILT(v, mm) (((v) == (mm) && (v) > 0.0f) ? fminf((v), clampv) : 0.0f)
    v4f o0, o1, o2, o3;
    o0.x = FILT(v0.x, m.x); o0.y = FILT(v0.y, m.y); o0.z = FILT(v0.z, m.z); o0.w = FILT(v0.w, m.w);
    o1.x = FILT(v1.x, m.x); o1.y = FILT(v1.y, m.y); o1.z = FILT(v1.z, m.z); o1.w = FILT(v1.w, m.w);
    o2.x = FILT(v2.x, m.x); o2.y = FILT(v2.y, m.y); o2.z = FILT(v2.z, m.z); o2.w = FILT(v2.w, m.w);
    o3.x = FILT(v3.x, m.x); o3.y = FILT(v3.y, m.y); o3.z = FILT(v3.z, m.z); o3.w = FILT(v3.w, m.w);
#undef FILT

    __builtin_nontemporal_store(o0, (v4f*)(out + base));
    __builtin_nontemporal_store(o1, (v4f*)(out + base + SPATIAL));
    __builtin_nontemporal_store(o2, (v4f*)(out + base + 2 * SPATIAL));
    __builtin_nontemporal_store(o3, (v4f*)(out + base + 3 * SPATIAL));
}

extern "C" void kernel_launch(void* const* d_in, const int* in_sizes, int n_in,
                              void* d_out, int out_size, void* d_ws, size_t ws_size,
                              hipStream_t stream) {
    const float* x = (const float*)d_in[0];
    // d_in[1] = group_size (int, ==4, structural — hardcoded)
    const float* max_clamp_p = (const float*)d_in[2];
    float* out = (float*)d_out;

    const int total_threads = GROUPS_TOTAL * SPATIAL4;  // 1,605,632
    const int block = 256;
    const int grid = total_threads / block;             // 6272, exact
    CGM_16707422781821_kernel<<<grid, block, 0, stream>>>(x, out, max_clamp_p);
}